// Round 8
// baseline (11660.659 us; speedup 1.0000x reference)
//
#include <hip/hip_runtime.h>
#include <cstdint>

#define T_STEPS 400
#define B_SZ    256
#define NIN_SZ  64
#define H_SZ    512
#define NOUT_SZ 16
#define NEXC    409            // int(0.8*512)
#define MEMBERS 8              // column-slice members per group
#define BG      2              // batches per group
#define CSL     64             // columns per member
#define NTHR    256
#define NBLK    ((B_SZ / BG) * MEMBERS)   // 128 groups x 8 = 1024 WGs, 4/CU
#define KEXT    576            // 512 recurrent + 64 input rows
#define KR      18             // K rows per thread-kg (576 / 32)
#define TAG_BASE 0x5A5A0000u

// 3-round cross-kg butterfly (lanes ^8,^16,^32 differ only in kg)
#define REDX(v)                                                        \
    v.x += __shfl_xor(v.x, 8);  v.y += __shfl_xor(v.y, 8);             \
    v.z += __shfl_xor(v.z, 8);  v.w += __shfl_xor(v.w, 8);             \
    v.x += __shfl_xor(v.x, 16); v.y += __shfl_xor(v.y, 16);            \
    v.z += __shfl_xor(v.z, 16); v.w += __shfl_xor(v.w, 16);            \
    v.x += __shfl_xor(v.x, 32); v.y += __shfl_xor(v.y, 32);            \
    v.z += __shfl_xor(v.z, 32); v.w += __shfl_xor(v.w, 32);

// NOTE: parameter names must not collide with member names x/y/z/w
// (the preprocessor substitutes identifiers even after '.') — R7 bug.
#define FMA4V(P, Q, s)                                                 \
    P.x = fmaf(Q.x, s, P.x); P.y = fmaf(Q.y, s, P.y);                  \
    P.z = fmaf(Q.z, s, P.z); P.w = fmaf(Q.w, s, P.w);

// ---------------------------------------------------------------------------
// 1024 WGs = 128 batch-groups x 8 column-members (members bid-adjacent).
// 4 WGs/CU: independent groups' compute hides each other's exchange latency.
// W slice (576 rows x 8 cols) in registers, asm-pinned vs rematerialization.
// h_post exchanged as (tag<<32)|value packets via sc0/sc1 global ops (IC-
// coherent and IC-cached; no fences, no invalidates, no flag round-trip).
// Exchange buffer = head of logits region of d_out (2.1 MB of 6.55 MB),
// overwritten by logits_k afterwards; tags can't collide with poison/logits.
// ---------------------------------------------------------------------------
__global__ __launch_bounds__(NTHR, 4)
void biornn_main(const float* __restrict__ x,
                 const float* __restrict__ noise,
                 const float* __restrict__ wrnn_raw,
                 const float* __restrict__ win_raw,
                 const float* __restrict__ brnn,
                 uint64_t* __restrict__ hpx,     // [2][B_SZ][H_SZ] tagged hp
                 float* __restrict__ out_h,
                 float* __restrict__ out_sx,
                 float* __restrict__ out_su)
{
    __shared__ __align__(16) float hpT[KEXT * BG];     // [k][b]   4.6 KB
    __shared__ __align__(16) float pbuf[4 * BG * 64];  // [wv][b][cc] 2 KB
    __shared__ float brnn_l[CSL];

    const int tid = threadIdx.x;
    const int bid = blockIdx.x;
    const int m   = bid & 7;           // member (column slice)
    const int g   = bid >> 3;          // batch group
    const int c0  = m * CSL;
    const int b0  = g * BG;

    const int kg  = tid >> 3;          // K-split group 0..31
    const int cg8 = (tid & 7) * 8;     // 8 owned cols within slice
    const int wv  = tid >> 6;          // wave 0..3
    const bool owner = (tid < BG * CSL);   // 128 owners: one (batch,col)
    const int cb  = tid >> 6;          // owner batch 0..1 (tid<128)
    const int cc  = tid & 63;          // owner local col

    // ---- one-time: W slice into registers (relu + Dale sign inline) ----
    float4 Wa[KR], Wb[KR];
#pragma unroll
    for (int i = 0; i < KR; ++i) {
        const int k = kg * KR + i;
        const float* src = (k < H_SZ)
            ? &wrnn_raw[(size_t)k * H_SZ + c0 + cg8]
            : &win_raw[(size_t)(k - H_SZ) * H_SZ + c0 + cg8];
        float4 va = *(const float4*)src;
        float4 vb = *(const float4*)(src + 4);
        const float sgn = (k < H_SZ && k >= NEXC) ? -1.0f : 1.0f;
        Wa[i] = make_float4(fmaxf(va.x, 0.f) * sgn, fmaxf(va.y, 0.f) * sgn,
                            fmaxf(va.z, 0.f) * sgn, fmaxf(va.w, 0.f) * sgn);
        Wb[i] = make_float4(fmaxf(vb.x, 0.f) * sgn, fmaxf(vb.y, 0.f) * sgn,
                            fmaxf(vb.z, 0.f) * sgn, fmaxf(vb.w, 0.f) * sgn);
    }
    // pin: asm-define W so the compiler cannot re-stream it per step (R4 bug)
#pragma unroll
    for (int i = 0; i < KR; ++i) {
        asm volatile("" : "+v"(Wa[i].x), "+v"(Wa[i].y),
                          "+v"(Wa[i].z), "+v"(Wa[i].w));
        asm volatile("" : "+v"(Wb[i].x), "+v"(Wb[i].y),
                          "+v"(Wb[i].z), "+v"(Wb[i].w));
    }
    if (tid < CSL) brnn_l[tid] = brnn[c0 + tid];

    // STP constants by column parity (owner col = c0+cc, c0 multiple of 64)
    const bool  fac   = ((tid & 1) == 0);
    const float Uj    = fac ? 0.15f : 0.45f;
    const float a_stf = fac ? (10.0f / 1500.0f) : (10.0f / 200.0f);
    const float a_std = fac ? (10.0f / 200.0f)  : (10.0f / 1500.0f);

    // ---- prologue: syn(0) from (h=0.1, sx=1, su=U); hp(0) by parity ----
    float h = 0.1f, sx, su;
    {
        float sxn = 1.0f - 0.01f * Uj * 1.0f * 0.1f;
        float sun = Uj + 0.01f * Uj * (1.0f - Uj) * 0.1f;
        sx = fminf(fmaxf(sxn, 0.0f), 1.0f);
        su = fminf(fmaxf(sun, 0.0f), 1.0f);
        // hp0 for even/odd columns (every thread computes both, picks per row)
        const float U_e = 0.15f, U_o = 0.45f;
        const float sx_e = 1.0f - 0.01f * U_e * 0.1f;
        const float su_e = U_e + 0.01f * U_e * (1.0f - U_e) * 0.1f;
        const float sx_o = 1.0f - 0.01f * U_o * 0.1f;
        const float su_o = U_o + 0.01f * U_o * (1.0f - U_o) * 0.1f;
        const float hp0_e = su_e * sx_e * 0.1f;
        const float hp0_o = su_o * sx_o * 0.1f;
#pragma unroll
        for (int r = tid; r < H_SZ; r += NTHR) {
            const float hp0 = (r & 1) ? hp0_o : hp0_e;
            hpT[r * BG + 0] = hp0;
            hpT[r * BG + 1] = hp0;
        }
        if (owner) {
            const size_t ob = (size_t)(b0 + cb) * H_SZ + c0 + cc;  // t = 0
            out_sx[ob] = sx;
            out_su[ob] = su;
        }
    }
    float xreg = 0.0f;
    if (owner) xreg = x[(size_t)(b0 + cb) * NIN_SZ + cc];   // x(0)

    for (int t = 0; t < T_STEPS; ++t) {
        // stage x(t) into hpT input rows (prefetched previous step)
        if (owner) hpT[(H_SZ + cc) * BG + cb] = xreg;
        __syncthreads();                                   // bar0: hpT(t) ready

        float nz = 0.0f;
        if (owner) nz = noise[((size_t)t * B_SZ + b0 + cb) * H_SZ + c0 + cc];

        // ---- phase B: matvec, W in registers, hpT broadcast reads ----
        float4 aA0 = make_float4(0.f, 0.f, 0.f, 0.f);
        float4 aB0 = aA0, aA1 = aA0, aB1 = aA0;
        {
            const float2* hp2 = (const float2*)hpT;
            const int kb = kg * KR;
#pragma unroll
            for (int i = 0; i < KR; ++i) {
                const float2 hv = hp2[kb + i];
                const float4 wa = Wa[i], wb = Wb[i];
                FMA4V(aA0, wa, hv.x)
                FMA4V(aB0, wb, hv.x)
                FMA4V(aA1, wa, hv.y)
                FMA4V(aB1, wb, hv.y)
            }
        }
        // prefetch x(t+1) while FMAs retire
        if (owner && t + 1 < T_STEPS)
            xreg = x[((size_t)(t + 1) * B_SZ + b0 + cb) * NIN_SZ + cc];

        // ---- cross-kg reduction: 8 kgs per wave via shuffles ----
        REDX(aA0) REDX(aB0) REDX(aA1) REDX(aB1)
        if ((tid & 56) == 0) {                 // lanes 0..7 of each wave
            *(float4*)&pbuf[(wv * BG + 0) * 64 + cg8]     = aA0;
            *(float4*)&pbuf[(wv * BG + 0) * 64 + cg8 + 4] = aB0;
            *(float4*)&pbuf[(wv * BG + 1) * 64 + cg8]     = aA1;
            *(float4*)&pbuf[(wv * BG + 1) * 64 + cg8 + 4] = aB1;
        }
        __syncthreads();                                   // bar1: pbuf ready

        // ---- phase C (owners): combine, membrane, STP(t+1), publish ----
        if (owner) {
            float s = brnn_l[cc];
#pragma unroll
            for (int q = 0; q < 4; ++q)
                s += pbuf[(q * BG + cb) * 64 + cc];
            const float hn = fmaxf(0.9f * h + 0.1f * s + nz, 0.0f);
            h = hn;
            if (t + 1 < T_STEPS) {
                float sxn = sx + a_std * (1.0f - sx) - 0.01f * su * sx * hn;
                float sun = su + a_stf * (Uj - su)   + 0.01f * Uj * (1.0f - su) * hn;
                sx = fminf(fmaxf(sxn, 0.0f), 1.0f);
                su = fminf(fmaxf(sun, 0.0f), 1.0f);
                const float hp = su * sx * hn;
                // publish FIRST (packets fly while outputs drain)
                const uint64_t pk =
                    ((uint64_t)(TAG_BASE + (unsigned)(t + 1)) << 32) |
                    (uint64_t)__float_as_uint(hp);
                uint64_t* sp = hpx +
                    ((size_t)((t + 1) & 1) * B_SZ + b0 + cb) * H_SZ + c0 + cc;
                asm volatile("global_store_dwordx2 %0, %1, off sc0 sc1"
                             :: "v"(sp), "v"(pk) : "memory");
                const size_t ob = ((size_t)(t + 1) * B_SZ + b0 + cb) * H_SZ + c0 + cc;
                out_sx[ob] = sx;
                out_su[ob] = su;
            }
            out_h[((size_t)t * B_SZ + b0 + cb) * H_SZ + c0 + cc] = hn;
        }
        if (t + 1 >= T_STEPS) break;

        // ---- gather hp(t+1): 2 rows x 2 batches per thread, tagged poll ----
        {
            const unsigned want = TAG_BASE + (unsigned)(t + 1);
            uint64_t* base = hpx + ((size_t)((t + 1) & 1) * B_SZ + b0) * H_SZ;
            uint64_t* p00 = base + tid;               // batch 0, row tid
            uint64_t* p01 = base + tid + 256;         // batch 0, row tid+256
            uint64_t* p10 = base + H_SZ + tid;        // batch 1, row tid
            uint64_t* p11 = base + H_SZ + tid + 256;  // batch 1, row tid+256
            uint64_t v00, v01, v10, v11;
            while (true) {
                asm volatile(
                    "global_load_dwordx2 %0, %4, off sc0 sc1\n\t"
                    "global_load_dwordx2 %1, %5, off sc0 sc1\n\t"
                    "global_load_dwordx2 %2, %6, off sc0 sc1\n\t"
                    "global_load_dwordx2 %3, %7, off sc0 sc1\n\t"
                    "s_waitcnt vmcnt(0)"
                    : "=&v"(v00), "=&v"(v01), "=&v"(v10), "=&v"(v11)
                    : "v"(p00), "v"(p01), "v"(p10), "v"(p11)
                    : "memory");
                const bool ok = ((unsigned)(v00 >> 32) == want) &
                                ((unsigned)(v01 >> 32) == want) &
                                ((unsigned)(v10 >> 32) == want) &
                                ((unsigned)(v11 >> 32) == want);
                if (__all(ok)) break;
                __builtin_amdgcn_s_sleep(1);
            }
            ((float2*)hpT)[tid] =
                make_float2(__uint_as_float((unsigned)v00),
                            __uint_as_float((unsigned)v10));
            ((float2*)hpT)[tid + 256] =
                make_float2(__uint_as_float((unsigned)v01),
                            __uint_as_float((unsigned)v11));
        }
        // next bar0 separates gather writes from phase-B reads
    }
}

// ---------------------------------------------------------------------------
// logits[t,b,:] = h[t,b,:] @ relu(W_out) + bout  (overwrites the hpx scratch)
// ---------------------------------------------------------------------------
__global__ __launch_bounds__(256)
void logits_k(const float* __restrict__ h, const float* __restrict__ wout_raw,
              const float* __restrict__ bout, float* __restrict__ out) {
    __shared__ float wl[H_SZ * 17];    // padded stride 17
    __shared__ float bl[NOUT_SZ];
    const int tid = threadIdx.x;
    for (int i = tid; i < H_SZ * NOUT_SZ; i += 256)
        wl[(i >> 4) * 17 + (i & 15)] = fmaxf(wout_raw[i], 0.0f);
    if (tid < NOUT_SZ) bl[tid] = bout[tid];
    __syncthreads();
    const size_t row = (size_t)blockIdx.x * 16 + (tid >> 4);
    const int o = tid & 15;
    const float* hr = h + row * H_SZ;
    float s = bl[o];
#pragma unroll 8
    for (int jj = 0; jj < H_SZ; ++jj)
        s = fmaf(hr[jj], wl[jj * 17 + o], s);
    out[row * NOUT_SZ + o] = s;
}

extern "C" void kernel_launch(void* const* d_in, const int* in_sizes, int n_in,
                              void* d_out, int out_size, void* d_ws, size_t ws_size,
                              hipStream_t stream) {
    const float* x     = (const float*)d_in[0];
    const float* noise = (const float*)d_in[1];
    const float* W_in  = (const float*)d_in[2];
    const float* W_rnn = (const float*)d_in[3];
    const float* b_rnn = (const float*)d_in[4];
    const float* W_out = (const float*)d_in[5];
    const float* b_out = (const float*)d_in[6];

    float* out_logits = (float*)d_out;
    float* out_h  = out_logits + (size_t)T_STEPS * B_SZ * NOUT_SZ;
    float* out_sx = out_h  + (size_t)T_STEPS * B_SZ * H_SZ;
    float* out_su = out_sx + (size_t)T_STEPS * B_SZ * H_SZ;

    // hp exchange scratch: first 2.1 MB of the logits region (6.55 MB);
    // logits_k fully overwrites it afterwards.
    uint64_t* hpx = (uint64_t*)out_logits;

    biornn_main<<<NBLK, NTHR, 0, stream>>>(x, noise, W_rnn, W_in, b_rnn,
                                           hpx, out_h, out_sx, out_su);
    logits_k<<<(T_STEPS * B_SZ) / 16, 256, 0, stream>>>(
        out_h, W_out, b_out, out_logits);
}

// Round 9
// 5566.617 us; speedup vs baseline: 2.0947x; 2.0947x over previous
//
#include <hip/hip_runtime.h>
#include <cstdint>

#define T_STEPS 400
#define B_SZ    256
#define NIN_SZ  64
#define H_SZ    512
#define NOUT_SZ 16
#define NEXC    409            // int(0.8*512)
#define MEMBERS 8              // column-slice members per group
#define BG      4              // batches per group
#define CSL     64             // columns per member
#define NTHR    512
#define NBLK    512            // 64 groups x 8 members; 2 WGs/CU
#define KEXT    576            // 512 recurrent + 64 input rows
#define KR      18             // K rows per thread-kg (576 / 32)
#define TAG_BASE 0x5A5A0000u

// cross-kg butterfly: kg bits are lane bits 4,5 (kg = tid>>4, 32 kgs)
#define RED4(v)                                                        \
    v.x += __shfl_xor(v.x, 16); v.y += __shfl_xor(v.y, 16);            \
    v.z += __shfl_xor(v.z, 16); v.w += __shfl_xor(v.w, 16);            \
    v.x += __shfl_xor(v.x, 32); v.y += __shfl_xor(v.y, 32);            \
    v.z += __shfl_xor(v.z, 32); v.w += __shfl_xor(v.w, 32);

// macro params must not collide with member names x/y/z/w (R7 lesson)
#define FMA4V(P, Q, s)                                                 \
    P.x = fmaf(Q.x, s, P.x); P.y = fmaf(Q.y, s, P.y);                  \
    P.z = fmaf(Q.z, s, P.z); P.w = fmaf(Q.w, s, P.w);

// ---------------------------------------------------------------------------
// 512 WGs = 64 batch-groups x 8 column-members.
// Mapping g=bid&63, m=bid>>6: co-resident WGs on a CU are DIFFERENT groups
// (independent timelines -> each hides the other's exchange latency), and a
// group's 8 members all share bid%8 -> same XCD.
// W slice (576x64 -> 72 floats/thread) in registers, asm-pinned; proven fit
// at 92 VGPR (R6). launch_bounds(512,4) caps at 128 so no spill is possible.
// h_post exchanged as (tag<<32)|value packets via sc0/sc1 global ops (IC-
// coherent and IC-cached; no fences, no invalidates, no flag round-trip).
// Exchange buffer = head of logits region of d_out (2 MB of 6.55 MB),
// overwritten by logits_k afterwards. Values are replay-invariant, so stale
// packets from a previous graph replay are benign; poison never matches tags.
// ---------------------------------------------------------------------------
__global__ __launch_bounds__(NTHR, 4)
void biornn_main(const float* __restrict__ x,
                 const float* __restrict__ noise,
                 const float* __restrict__ wrnn_raw,
                 const float* __restrict__ win_raw,
                 const float* __restrict__ brnn,
                 uint64_t* __restrict__ hpx,     // [2][B_SZ][H_SZ] tagged hp
                 float* __restrict__ out_h,
                 float* __restrict__ out_sx,
                 float* __restrict__ out_su)
{
    __shared__ __align__(16) float hpT[KEXT * BG];     // [k][b]   9.2 KB
    __shared__ __align__(16) float pbuf[8 * BG * 64];  // [wv][b][cc] 8 KB
    __shared__ float brnn_l[CSL];

    const int tid = threadIdx.x;
    const int bid = blockIdx.x;
    const int g   = bid & 63;          // batch group   (adjacent bids differ)
    const int m   = bid >> 6;          // member (column slice)
    const int c0  = m * CSL;
    const int b0  = g * BG;

    const int kg  = tid >> 4;          // K-split group 0..31
    const int cg4 = (tid & 15) * 4;    // 4 owned cols within slice
    const int wv  = tid >> 6;          // wave 0..7
    const bool owner = (tid < BG * CSL);   // 256 owners: one (batch,col)
    const int cb  = tid >> 6;          // owner batch 0..3 (tid<256)
    const int cc  = tid & 63;          // owner local col

    // ---- one-time: W slice into registers (relu + Dale sign inline) ----
    float4 Wv[KR];
#pragma unroll
    for (int i = 0; i < KR; ++i) {
        const int k = kg * KR + i;
        const float* src = (k < H_SZ)
            ? &wrnn_raw[(size_t)k * H_SZ + c0 + cg4]
            : &win_raw[(size_t)(k - H_SZ) * H_SZ + c0 + cg4];
        float4 v = *(const float4*)src;
        const float sgn = (k < H_SZ && k >= NEXC) ? -1.0f : 1.0f;
        Wv[i] = make_float4(fmaxf(v.x, 0.f) * sgn, fmaxf(v.y, 0.f) * sgn,
                            fmaxf(v.z, 0.f) * sgn, fmaxf(v.w, 0.f) * sgn);
    }
    // pin: asm-define W so the compiler cannot re-stream it per step
#pragma unroll
    for (int i = 0; i < KR; ++i)
        asm volatile("" : "+v"(Wv[i].x), "+v"(Wv[i].y),
                          "+v"(Wv[i].z), "+v"(Wv[i].w));

    if (tid < CSL) brnn_l[tid] = brnn[c0 + tid];

    // STP constants by column parity (c0 is a multiple of 64; parity(tid)
    // equals parity of row tid and of owner column c0+cc)
    const bool  fac   = ((tid & 1) == 0);
    const float Uj    = fac ? 0.15f : 0.45f;
    const float a_stf = fac ? (10.0f / 1500.0f) : (10.0f / 200.0f);
    const float a_std = fac ? (10.0f / 200.0f)  : (10.0f / 1500.0f);

    // ---- prologue: syn(0) from (h=0.1, sx=1, su=U); hp(0) uniform/parity ----
    float h = 0.1f, sx, su;
    {
        float sxn = 1.0f - 0.01f * Uj * 1.0f * 0.1f;
        float sun = Uj + 0.01f * Uj * (1.0f - Uj) * 0.1f;
        sx = fminf(fmaxf(sxn, 0.0f), 1.0f);
        su = fminf(fmaxf(sun, 0.0f), 1.0f);
        const float hp0 = su * sx * 0.1f;      // row parity == tid parity
        ((float4*)hpT)[tid] = make_float4(hp0, hp0, hp0, hp0);
        if (owner) {
            const size_t ob = (size_t)(b0 + cb) * H_SZ + c0 + cc;  // t = 0
            out_sx[ob] = sx;
            out_su[ob] = su;
        }
    }
    float xreg = 0.0f;
    if (tid < BG * NIN_SZ)             // 256 stagers: (batch tid>>6, in tid&63)
        xreg = x[(size_t)(b0 + (tid >> 6)) * NIN_SZ + (tid & 63)];

    for (int t = 0; t < T_STEPS; ++t) {
        // stage x(t) into hpT input rows (prefetched previous step)
        if (tid < BG * NIN_SZ) hpT[(H_SZ + (tid & 63)) * BG + (tid >> 6)] = xreg;
        __syncthreads();                                   // bar0: hpT(t) ready

        float nz = 0.0f;
        if (owner) nz = noise[((size_t)t * B_SZ + b0 + cb) * H_SZ + c0 + cc];

        // ---- phase B: matvec, W in registers, hpT broadcast reads ----
        float4 a0 = make_float4(0.f, 0.f, 0.f, 0.f), a1 = a0, a2 = a0, a3 = a0;
        {
            const float4* hp4 = (const float4*)hpT;
            const int kb = kg * KR;
#pragma unroll
            for (int i = 0; i < KR; ++i) {
                const float4 hv = hp4[kb + i];     // 4 batches of row kb+i
                const float4 wq = Wv[i];           // 4 cols
                FMA4V(a0, wq, hv.x)
                FMA4V(a1, wq, hv.y)
                FMA4V(a2, wq, hv.z)
                FMA4V(a3, wq, hv.w)
            }
        }
        // prefetch x(t+1) while FMAs retire
        if (tid < BG * NIN_SZ && t + 1 < T_STEPS)
            xreg = x[((size_t)(t + 1) * B_SZ + b0 + (tid >> 6)) * NIN_SZ + (tid & 63)];

        // ---- cross-kg reduction: 4 kgs per wave via shuffles ----
        RED4(a0) RED4(a1) RED4(a2) RED4(a3)
        if ((tid & 48) == 0) {                 // lanes 0..15 of each wave
            *(float4*)&pbuf[(wv * BG + 0) * 64 + cg4] = a0;
            *(float4*)&pbuf[(wv * BG + 1) * 64 + cg4] = a1;
            *(float4*)&pbuf[(wv * BG + 2) * 64 + cg4] = a2;
            *(float4*)&pbuf[(wv * BG + 3) * 64 + cg4] = a3;
        }
        __syncthreads();                                   // bar1: pbuf ready

        // ---- phase C (owners): combine, membrane, STP(t+1), publish ----
        if (owner) {
            float s = brnn_l[cc];
#pragma unroll
            for (int q = 0; q < 8; ++q)
                s += pbuf[(q * BG + cb) * 64 + cc];
            const float hn = fmaxf(0.9f * h + 0.1f * s + nz, 0.0f);
            h = hn;
            if (t + 1 < T_STEPS) {
                float sxn = sx + a_std * (1.0f - sx) - 0.01f * su * sx * hn;
                float sun = su + a_stf * (Uj - su)   + 0.01f * Uj * (1.0f - su) * hn;
                sx = fminf(fmaxf(sxn, 0.0f), 1.0f);
                su = fminf(fmaxf(sun, 0.0f), 1.0f);
                const float hp = su * sx * hn;
                // publish immediately: packets fly while peers finish
                const uint64_t pk =
                    ((uint64_t)(TAG_BASE + (unsigned)(t + 1)) << 32) |
                    (uint64_t)__float_as_uint(hp);
                uint64_t* sp = hpx +
                    ((size_t)((t + 1) & 1) * B_SZ + b0 + cb) * H_SZ + c0 + cc;
                asm volatile("global_store_dwordx2 %0, %1, off sc0 sc1"
                             :: "v"(sp), "v"(pk) : "memory");
            }
        }
        if (t + 1 >= T_STEPS) {
            if (owner)
                out_h[((size_t)t * B_SZ + b0 + cb) * H_SZ + c0 + cc] = h;
            break;
        }

        // ---- gather hp(t+1): row tid x 4 batches, tagged poll via IC ----
        {
            const unsigned want = TAG_BASE + (unsigned)(t + 1);
            uint64_t* p0 = hpx + ((size_t)((t + 1) & 1) * B_SZ + b0) * H_SZ + tid;
            uint64_t* p1 = p0 + H_SZ;
            uint64_t* p2 = p0 + 2 * H_SZ;
            uint64_t* p3 = p0 + 3 * H_SZ;
            uint64_t v0, v1, v2, v3;
            while (true) {
                asm volatile(
                    "global_load_dwordx2 %0, %4, off sc0 sc1\n\t"
                    "global_load_dwordx2 %1, %5, off sc0 sc1\n\t"
                    "global_load_dwordx2 %2, %6, off sc0 sc1\n\t"
                    "global_load_dwordx2 %3, %7, off sc0 sc1\n\t"
                    "s_waitcnt vmcnt(0)"
                    : "=&v"(v0), "=&v"(v1), "=&v"(v2), "=&v"(v3)
                    : "v"(p0), "v"(p1), "v"(p2), "v"(p3)
                    : "memory");
                const bool ok = ((unsigned)(v0 >> 32) == want) &
                                ((unsigned)(v1 >> 32) == want) &
                                ((unsigned)(v2 >> 32) == want) &
                                ((unsigned)(v3 >> 32) == want);
                if (__all(ok)) break;
                __builtin_amdgcn_s_sleep(1);
            }
            ((float4*)hpT)[tid] =
                make_float4(__uint_as_float((unsigned)v0),
                            __uint_as_float((unsigned)v1),
                            __uint_as_float((unsigned)v2),
                            __uint_as_float((unsigned)v3));
        }

        // ---- outputs AFTER the poll: their latency overlaps step t+1,
        // and the poll's vmcnt(0) no longer waits on them ----
        if (owner) {
            out_h[((size_t)t * B_SZ + b0 + cb) * H_SZ + c0 + cc] = h;
            const size_t ob = ((size_t)(t + 1) * B_SZ + b0 + cb) * H_SZ + c0 + cc;
            out_sx[ob] = sx;
            out_su[ob] = su;
        }
        // next bar0 separates gather/x writes from phase-B reads
    }
}

// ---------------------------------------------------------------------------
// logits[t,b,:] = h[t,b,:] @ relu(W_out) + bout  (overwrites the hpx scratch)
// ---------------------------------------------------------------------------
__global__ __launch_bounds__(256)
void logits_k(const float* __restrict__ h, const float* __restrict__ wout_raw,
              const float* __restrict__ bout, float* __restrict__ out) {
    __shared__ float wl[H_SZ * 17];    // padded stride 17
    __shared__ float bl[NOUT_SZ];
    const int tid = threadIdx.x;
    for (int i = tid; i < H_SZ * NOUT_SZ; i += 256)
        wl[(i >> 4) * 17 + (i & 15)] = fmaxf(wout_raw[i], 0.0f);
    if (tid < NOUT_SZ) bl[tid] = bout[tid];
    __syncthreads();
    const size_t row = (size_t)blockIdx.x * 16 + (tid >> 4);
    const int o = tid & 15;
    const float* hr = h + row * H_SZ;
    float s = bl[o];
#pragma unroll 8
    for (int jj = 0; jj < H_SZ; ++jj)
        s = fmaf(hr[jj], wl[jj * 17 + o], s);
    out[row * NOUT_SZ + o] = s;
}

extern "C" void kernel_launch(void* const* d_in, const int* in_sizes, int n_in,
                              void* d_out, int out_size, void* d_ws, size_t ws_size,
                              hipStream_t stream) {
    const float* x     = (const float*)d_in[0];
    const float* noise = (const float*)d_in[1];
    const float* W_in  = (const float*)d_in[2];
    const float* W_rnn = (const float*)d_in[3];
    const float* b_rnn = (const float*)d_in[4];
    const float* W_out = (const float*)d_in[5];
    const float* b_out = (const float*)d_in[6];

    float* out_logits = (float*)d_out;
    float* out_h  = out_logits + (size_t)T_STEPS * B_SZ * NOUT_SZ;
    float* out_sx = out_h  + (size_t)T_STEPS * B_SZ * H_SZ;
    float* out_su = out_sx + (size_t)T_STEPS * B_SZ * H_SZ;

    // hp exchange scratch: first 2 MB of the logits region (6.55 MB);
    // logits_k fully overwrites it afterwards.
    uint64_t* hpx = (uint64_t*)out_logits;

    biornn_main<<<NBLK, NTHR, 0, stream>>>(x, noise, W_rnn, W_in, b_rnn,
                                           hpx, out_h, out_sx, out_su);
    logits_k<<<(T_STEPS * B_SZ) / 16, 256, 0, stream>>>(
        out_h, W_out, b_out, out_logits);
}

// Round 11
// 3061.326 us; speedup vs baseline: 3.8090x; 1.8184x over previous
//
#include <hip/hip_runtime.h>
#include <cstdint>

#define T_STEPS 400
#define B_SZ    256
#define NIN_SZ  64
#define H_SZ    512
#define NOUT_SZ 16
#define NEXC    409            // int(0.8*512)
#define MEMBERS 8              // column-slice members per group
#define GROUPS  32             // batch groups
#define BG      8              // batches per group
#define CSL     64             // columns per member
#define NTHR    512
#define NBLK    (GROUPS * MEMBERS)   // 256 WGs = 1 per CU (guaranteed resident)
#define KEXT    576            // 512 recurrent + 64 input rows
#define KR      18             // K rows per thread-kg (576 / 32)

// cross-kg butterfly: kg low bits are lane bits 4,5 (kg = tid>>4)
#define RED4(v)                                                        \
    v.x += __shfl_xor(v.x, 16); v.y += __shfl_xor(v.y, 16);            \
    v.z += __shfl_xor(v.z, 16); v.w += __shfl_xor(v.w, 16);            \
    v.x += __shfl_xor(v.x, 32); v.y += __shfl_xor(v.y, 32);            \
    v.z += __shfl_xor(v.z, 32); v.w += __shfl_xor(v.w, 32);

// macro params must not collide with member names x/y/z/w (R7 lesson)
#define FMA4V(P, Q, s)                                                 \
    P.x = fmaf(Q.x, s, P.x); P.y = fmaf(Q.y, s, P.y);                  \
    P.z = fmaf(Q.z, s, P.z); P.w = fmaf(Q.w, s, P.w);

__global__ void zero_flags(unsigned int* __restrict__ flags) {
    if (threadIdx.x < NBLK) flags[threadIdx.x] = 0u;
}

// ---------------------------------------------------------------------------
// 256 WGs = 32 batch-groups x 8 column-members, member-ADJACENT bids
// (m=bid&7): a group's members dispatch together and the whole grid fits
// 1 WG/CU -> co-residency guaranteed, no deadlock (R10 lesson: never
// scatter a sync-group across distant bids).
// W slice (576x64, 72 floats/thread) in registers, asm-pinned.
// CODEGEN LAW (R4..R10): only __launch_bounds__(512,2) holds W resident
// (~128 VGPR, FETCH ~0.24 GB). Any tighter bound clamps to 64 VGPR and
// spills W to scratch (11-37 GB FETCH, 2-5x slower). Do not "optimize".
// Sync per step: raw 4B sc0/sc1 packet stores -> vmcnt(0) (own store only)
// -> barrier -> 1 flag store/member -> 8 threads poll 8 flags (cheap
// sweeps; R6's all-thread tagged polling saturated IC bandwidth) ->
// barrier -> coalesced gather. Flags monotonic in d_ws, zeroed per launch;
// producer skew <= 1 step -> parity-2 packet buffer is safe.
// ---------------------------------------------------------------------------
__global__ __launch_bounds__(NTHR, 2)
void biornn_main(const float* __restrict__ x,
                 const float* __restrict__ noise,
                 const float* __restrict__ wrnn_raw,
                 const float* __restrict__ win_raw,
                 const float* __restrict__ brnn,
                 float* __restrict__ pkt,        // [2][B_SZ][H_SZ] hp exchange
                 unsigned int* __restrict__ flags,   // [GROUPS*MEMBERS]
                 float* __restrict__ out_h,
                 float* __restrict__ out_sx,
                 float* __restrict__ out_su)
{
    __shared__ __align__(16) float hpT[KEXT * BG];     // [k][b]  18 KB
    __shared__ __align__(16) float pbuf[8 * BG * 64];  // [wv][b][cc] 16 KB
    __shared__ float brnn_l[CSL];

    const int tid = threadIdx.x;
    const int bid = blockIdx.x;
    const int m   = bid & 7;           // member (column slice) — adjacent!
    const int g   = bid >> 3;          // batch group
    const int c0  = m * CSL;
    const int b0  = g * BG;

    const int kg  = tid >> 4;          // K-split group 0..31
    const int cg4 = (tid & 15) * 4;    // 4 owned cols within slice
    const int wv  = tid >> 6;          // wave 0..7
    const int cb  = tid >> 6;          // owner batch 0..7 (all 512 own a pair)
    const int cc  = tid & 63;          // owner local col

    // ---- one-time: W slice into registers (relu + Dale sign inline) ----
    float4 Wv[KR];
#pragma unroll
    for (int i = 0; i < KR; ++i) {
        const int k = kg * KR + i;
        const float* src = (k < H_SZ)
            ? &wrnn_raw[(size_t)k * H_SZ + c0 + cg4]
            : &win_raw[(size_t)(k - H_SZ) * H_SZ + c0 + cg4];
        float4 v = *(const float4*)src;
        const float sgn = (k < H_SZ && k >= NEXC) ? -1.0f : 1.0f;
        Wv[i] = make_float4(fmaxf(v.x, 0.f) * sgn, fmaxf(v.y, 0.f) * sgn,
                            fmaxf(v.z, 0.f) * sgn, fmaxf(v.w, 0.f) * sgn);
    }
#pragma unroll
    for (int i = 0; i < KR; ++i)       // pin vs rematerialization (R4 bug)
        asm volatile("" : "+v"(Wv[i].x), "+v"(Wv[i].y),
                          "+v"(Wv[i].z), "+v"(Wv[i].w));

    if (tid < CSL) brnn_l[tid] = brnn[c0 + tid];

    // STP constants by column parity (c0 multiple of 64 -> parity(tid) works
    // for both hpT row tid and owner column c0+cc)
    const bool  fac   = ((tid & 1) == 0);
    const float Uj    = fac ? 0.15f : 0.45f;
    const float a_stf = fac ? (10.0f / 1500.0f) : (10.0f / 200.0f);
    const float a_std = fac ? (10.0f / 200.0f)  : (10.0f / 1500.0f);

    // ---- prologue: syn(0) from (h=0.1, sx=1, su=U); hp(0) by parity ----
    float h = 0.1f, sx, su;
    {
        float sxn = 1.0f - 0.01f * Uj * 1.0f * 0.1f;
        float sun = Uj + 0.01f * Uj * (1.0f - Uj) * 0.1f;
        sx = fminf(fmaxf(sxn, 0.0f), 1.0f);
        su = fminf(fmaxf(sun, 0.0f), 1.0f);
        const float hp0 = su * sx * 0.1f;      // row parity == tid parity
        ((float4*)hpT)[tid * 2]     = make_float4(hp0, hp0, hp0, hp0);
        ((float4*)hpT)[tid * 2 + 1] = make_float4(hp0, hp0, hp0, hp0);
        const size_t ob = (size_t)(b0 + cb) * H_SZ + c0 + cc;      // t = 0
        out_sx[ob] = sx;
        out_su[ob] = su;
    }
    // x stagers: all 512 threads, (batch tid>>6, input col tid&63)
    float xreg = x[(size_t)(b0 + (tid >> 6)) * NIN_SZ + (tid & 63)];

    for (int t = 0; t < T_STEPS; ++t) {
        // stage x(t) into hpT input rows (prefetched previous step)
        hpT[(H_SZ + (tid & 63)) * BG + (tid >> 6)] = xreg;
        __syncthreads();                                   // bar0: hpT(t) ready

        const float nz = noise[((size_t)t * B_SZ + b0 + cb) * H_SZ + c0 + cc];

        // ---- phase B: matvec, W in registers, hpT broadcast reads ----
        float4 a0 = make_float4(0.f, 0.f, 0.f, 0.f);
        float4 a1 = a0, a2 = a0, a3 = a0, a4 = a0, a5 = a0, a6 = a0, a7 = a0;
        {
            const float4* hp4 = (const float4*)hpT;
            const int kb = kg * KR;
#pragma unroll
            for (int i = 0; i < KR; ++i) {
                const float4 hL = hp4[(kb + i) * 2];       // batches 0..3
                const float4 hH = hp4[(kb + i) * 2 + 1];   // batches 4..7
                const float4 wq = Wv[i];
                FMA4V(a0, wq, hL.x)
                FMA4V(a1, wq, hL.y)
                FMA4V(a2, wq, hL.z)
                FMA4V(a3, wq, hL.w)
                FMA4V(a4, wq, hH.x)
                FMA4V(a5, wq, hH.y)
                FMA4V(a6, wq, hH.z)
                FMA4V(a7, wq, hH.w)
            }
        }
        // prefetch x(t+1) while FMAs retire
        if (t + 1 < T_STEPS)
            xreg = x[((size_t)(t + 1) * B_SZ + b0 + (tid >> 6)) * NIN_SZ + (tid & 63)];

        // ---- cross-kg reduction: 4 kgs per wave via shuffles ----
        RED4(a0) RED4(a1) RED4(a2) RED4(a3)
        RED4(a4) RED4(a5) RED4(a6) RED4(a7)
        if ((tid & 48) == 0) {                 // lanes 0..15 of each wave
            *(float4*)&pbuf[(wv * BG + 0) * 64 + cg4] = a0;
            *(float4*)&pbuf[(wv * BG + 1) * 64 + cg4] = a1;
            *(float4*)&pbuf[(wv * BG + 2) * 64 + cg4] = a2;
            *(float4*)&pbuf[(wv * BG + 3) * 64 + cg4] = a3;
            *(float4*)&pbuf[(wv * BG + 4) * 64 + cg4] = a4;
            *(float4*)&pbuf[(wv * BG + 5) * 64 + cg4] = a5;
            *(float4*)&pbuf[(wv * BG + 6) * 64 + cg4] = a6;
            *(float4*)&pbuf[(wv * BG + 7) * 64 + cg4] = a7;
        }
        __syncthreads();                                   // bar1: pbuf ready

        // ---- phase C: combine, membrane, STP(t+1), publish packet ----
        {
            float s = brnn_l[cc];
#pragma unroll
            for (int q = 0; q < 8; ++q)
                s += pbuf[(q * BG + cb) * 64 + cc];
            const float hn = fmaxf(0.9f * h + 0.1f * s + nz, 0.0f);
            h = hn;
            if (t + 1 < T_STEPS) {
                float sxn = sx + a_std * (1.0f - sx) - 0.01f * su * sx * hn;
                float sun = su + a_stf * (Uj - su)   + 0.01f * Uj * (1.0f - su) * hn;
                sx = fminf(fmaxf(sxn, 0.0f), 1.0f);
                su = fminf(fmaxf(sun, 0.0f), 1.0f);
                const float hp = su * sx * hn;
                float* sp = pkt +
                    ((size_t)((t + 1) & 1) * B_SZ + b0 + cb) * H_SZ + c0 + cc;
                asm volatile("global_store_dword %0, %1, off sc0 sc1"
                             :: "v"(sp), "v"(hp) : "memory");
            }
        }
        if (t + 1 >= T_STEPS) {
            out_h[((size_t)t * B_SZ + b0 + cb) * H_SZ + c0 + cc] = h;
            break;
        }

        // ---- release: drain own packet store, then one flag per member ----
        asm volatile("s_waitcnt vmcnt(0)" ::: "memory");
        __syncthreads();                       // all 512 packets at IC
        if (tid == 0) {
            unsigned int* fp = flags + bid;    // = g*8 + m
            unsigned int  fv = (unsigned)(t + 1);
            asm volatile("global_store_dword %0, %1, off sc0 sc1"
                         :: "v"(fp), "v"(fv) : "memory");
        }
        // ---- acquire: 8 threads poll the group's 8 member flags ----
        if (tid < MEMBERS) {
            const unsigned want = (unsigned)(t + 1);
            const unsigned int* fp = flags + g * MEMBERS + tid;
            unsigned int v;
            while (true) {
                asm volatile("global_load_dword %0, %1, off sc0 sc1\n\t"
                             "s_waitcnt vmcnt(0)"
                             : "=v"(v) : "v"(fp) : "memory");
                if (v >= want) break;
                __builtin_amdgcn_s_sleep(1);
            }
        }
        __syncthreads();

        // ---- gather hp(t+1): row tid x 8 batches, coalesced sc0/sc1 ----
        {
            const float* q0 = pkt + ((size_t)((t + 1) & 1) * B_SZ + b0) * H_SZ + tid;
            const float* q2 = q0 + 2 * H_SZ;
            const float* q4 = q0 + 4 * H_SZ;
            const float* q6 = q0 + 6 * H_SZ;
            float g0, g1, g2, g3, g4, g5, g6, g7;
            asm volatile(
                "global_load_dword %0, %8,  off sc0 sc1\n\t"
                "global_load_dword %1, %8,  off offset:2048 sc0 sc1\n\t"
                "global_load_dword %2, %9,  off sc0 sc1\n\t"
                "global_load_dword %3, %9,  off offset:2048 sc0 sc1\n\t"
                "global_load_dword %4, %10, off sc0 sc1\n\t"
                "global_load_dword %5, %10, off offset:2048 sc0 sc1\n\t"
                "global_load_dword %6, %11, off sc0 sc1\n\t"
                "global_load_dword %7, %11, off offset:2048 sc0 sc1\n\t"
                "s_waitcnt vmcnt(0)"
                : "=&v"(g0), "=&v"(g1), "=&v"(g2), "=&v"(g3),
                  "=&v"(g4), "=&v"(g5), "=&v"(g6), "=&v"(g7)
                : "v"(q0), "v"(q2), "v"(q4), "v"(q6)
                : "memory");
            ((float4*)hpT)[tid * 2]     = make_float4(g0, g1, g2, g3);
            ((float4*)hpT)[tid * 2 + 1] = make_float4(g4, g5, g6, g7);
        }

        // ---- outputs AFTER the sync: latency overlaps step t+1 ----
        {
            out_h[((size_t)t * B_SZ + b0 + cb) * H_SZ + c0 + cc] = h;
            const size_t ob = ((size_t)(t + 1) * B_SZ + b0 + cb) * H_SZ + c0 + cc;
            out_sx[ob] = sx;
            out_su[ob] = su;
        }
        // next bar0 separates gather/x-stage writes from phase-B reads
    }
}

// ---------------------------------------------------------------------------
// logits[t,b,:] = h[t,b,:] @ relu(W_out) + bout  (overwrites the pkt scratch)
// ---------------------------------------------------------------------------
__global__ __launch_bounds__(256)
void logits_k(const float* __restrict__ h, const float* __restrict__ wout_raw,
              const float* __restrict__ bout, float* __restrict__ out) {
    __shared__ float wl[H_SZ * 17];    // padded stride 17
    __shared__ float bl[NOUT_SZ];
    const int tid = threadIdx.x;
    for (int i = tid; i < H_SZ * NOUT_SZ; i += 256)
        wl[(i >> 4) * 17 + (i & 15)] = fmaxf(wout_raw[i], 0.0f);
    if (tid < NOUT_SZ) bl[tid] = bout[tid];
    __syncthreads();
    const size_t row = (size_t)blockIdx.x * 16 + (tid >> 4);
    const int o = tid & 15;
    const float* hr = h + row * H_SZ;
    float s = bl[o];
#pragma unroll 8
    for (int jj = 0; jj < H_SZ; ++jj)
        s = fmaf(hr[jj], wl[jj * 17 + o], s);
    out[row * NOUT_SZ + o] = s;
}

extern "C" void kernel_launch(void* const* d_in, const int* in_sizes, int n_in,
                              void* d_out, int out_size, void* d_ws, size_t ws_size,
                              hipStream_t stream) {
    const float* x     = (const float*)d_in[0];
    const float* noise = (const float*)d_in[1];
    const float* W_in  = (const float*)d_in[2];
    const float* W_rnn = (const float*)d_in[3];
    const float* b_rnn = (const float*)d_in[4];
    const float* W_out = (const float*)d_in[5];
    const float* b_out = (const float*)d_in[6];

    float* out_logits = (float*)d_out;
    float* out_h  = out_logits + (size_t)T_STEPS * B_SZ * NOUT_SZ;
    float* out_sx = out_h  + (size_t)T_STEPS * B_SZ * H_SZ;
    float* out_su = out_sx + (size_t)T_STEPS * B_SZ * H_SZ;

    // hp packet scratch: first 1 MB of the 6.55 MB logits region (fully
    // overwritten by logits_k afterwards). Flags live in d_ws, zeroed per
    // launch so graph replays start clean.
    float* pkt = out_logits;
    unsigned int* flags = (unsigned int*)d_ws;

    zero_flags<<<1, 256, 0, stream>>>(flags);
    biornn_main<<<NBLK, NTHR, 0, stream>>>(x, noise, W_rnn, W_in, b_rnn,
                                           pkt, flags, out_h, out_sx, out_su);
    logits_k<<<(T_STEPS * B_SZ) / 16, 256, 0, stream>>>(
        out_h, W_out, b_out, out_logits);
}

// Round 12
// 2335.174 us; speedup vs baseline: 4.9935x; 1.3110x over previous
//
#include <hip/hip_runtime.h>
#include <cstdint>

#define T_STEPS 400
#define B_SZ    256
#define NIN_SZ  64
#define H_SZ    512
#define NOUT_SZ 16
#define NEXC    409            // int(0.8*512)
#define MEMBERS 8              // column-slice members per group
#define GROUPS  32             // batch groups
#define BG      8              // batches per group
#define CSL     64             // columns per member
#define NTHR    512
#define NBLK    (GROUPS * MEMBERS)   // 256 WGs = 1/CU, all resident: no deadlock
#define KEXT    576            // 512 recurrent + 64 input rows
#define KR      18             // K rows per thread-kg (576 / 32)
#define TAG_BASE 0x5A5A0000u

// cross-kg butterfly: kg low bits are lane bits 4,5 (kg = tid>>4)
#define RED4(v)                                                        \
    v.x += __shfl_xor(v.x, 16); v.y += __shfl_xor(v.y, 16);            \
    v.z += __shfl_xor(v.z, 16); v.w += __shfl_xor(v.w, 16);            \
    v.x += __shfl_xor(v.x, 32); v.y += __shfl_xor(v.y, 32);            \
    v.z += __shfl_xor(v.z, 32); v.w += __shfl_xor(v.w, 32);

// macro params must not collide with member names x/y/z/w (R7 lesson)
#define FMA4V(P, Q, s)                                                 \
    P.x = fmaf(Q.x, s, P.x); P.y = fmaf(Q.y, s, P.y);                  \
    P.z = fmaf(Q.z, s, P.z); P.w = fmaf(Q.w, s, P.w);

// ---------------------------------------------------------------------------
// 256 WGs = 32 batch-groups x 8 column-members. m=bid>>5, g=bid&31:
// a group's members occupy bids {g, g+32, ..., g+224} -> all share bid%8
// -> SAME XCD (short coherence hops); grid == CU count -> every WG resident
// -> deadlock-free regardless of mapping (R10 lesson).
// W slice (576x64, 72 floats/thread) in registers, asm-pinned.
// CODEGEN LAW (R4..R11): only __launch_bounds__(512,2) holds W resident.
// Tighter bounds clamp to 64 VGPR and spill W to scratch (2-5x slower).
// Exchange: tagged (tag<<32)|hp 8B packets via sc0/sc1 (IC-coherent) —
// NO flags, NO release fence/drain, NO extra barriers. Consumers poll the
// data. Skew bound 1 step -> parity-2 buffer safe. Tags/values are replay-
// invariant (stale packet == correct value); logits/poison never alias tags.
// Poll hygiene: one vmcnt(0) drains outputs+prefetch BEFORE polling so poll
// iterations wait only on their own 8 loads.
// ---------------------------------------------------------------------------
__global__ __launch_bounds__(NTHR, 2)
void biornn_main(const float* __restrict__ x,
                 const float* __restrict__ noise,
                 const float* __restrict__ wrnn_raw,
                 const float* __restrict__ win_raw,
                 const float* __restrict__ brnn,
                 uint64_t* __restrict__ pkt,     // [2][B_SZ][H_SZ] tagged hp
                 float* __restrict__ out_h,
                 float* __restrict__ out_sx,
                 float* __restrict__ out_su)
{
    __shared__ __align__(16) float hpT[KEXT * BG];     // [k][b]  18 KB
    __shared__ __align__(16) float pbuf[8 * BG * 64];  // [wv][b][cc] 16 KB
    __shared__ float brnn_l[CSL];

    const int tid = threadIdx.x;
    const int bid = blockIdx.x;
    const int m   = bid >> 5;          // member slice; group shares XCD
    const int g   = bid & 31;          // batch group
    const int c0  = m * CSL;
    const int b0  = g * BG;

    const int kg  = tid >> 4;          // K-split group 0..31
    const int cg4 = (tid & 15) * 4;    // 4 owned cols within slice
    const int wv  = tid >> 6;          // wave 0..7
    const int cb  = tid >> 6;          // owner batch 0..7
    const int cc  = tid & 63;          // owner local col

    // ---- one-time: W slice into registers (relu + Dale sign inline) ----
    float4 Wv[KR];
#pragma unroll
    for (int i = 0; i < KR; ++i) {
        const int k = kg * KR + i;
        const float* src = (k < H_SZ)
            ? &wrnn_raw[(size_t)k * H_SZ + c0 + cg4]
            : &win_raw[(size_t)(k - H_SZ) * H_SZ + c0 + cg4];
        float4 v = *(const float4*)src;
        const float sgn = (k < H_SZ && k >= NEXC) ? -1.0f : 1.0f;
        Wv[i] = make_float4(fmaxf(v.x, 0.f) * sgn, fmaxf(v.y, 0.f) * sgn,
                            fmaxf(v.z, 0.f) * sgn, fmaxf(v.w, 0.f) * sgn);
    }
#pragma unroll
    for (int i = 0; i < KR; ++i)       // pin vs rematerialization (R4 bug)
        asm volatile("" : "+v"(Wv[i].x), "+v"(Wv[i].y),
                          "+v"(Wv[i].z), "+v"(Wv[i].w));

    if (tid < CSL) brnn_l[tid] = brnn[c0 + tid];

    // STP constants by column parity (c0 multiple of 64 -> parity(tid) works
    // for both hpT row tid and owner column c0+cc)
    const bool  fac   = ((tid & 1) == 0);
    const float Uj    = fac ? 0.15f : 0.45f;
    const float a_stf = fac ? (10.0f / 1500.0f) : (10.0f / 200.0f);
    const float a_std = fac ? (10.0f / 200.0f)  : (10.0f / 1500.0f);

    // ---- prologue: syn(0) from (h=0.1, sx=1, su=U); hp(0) by parity ----
    float h = 0.1f, sx, su;
    {
        float sxn = 1.0f - 0.01f * Uj * 1.0f * 0.1f;
        float sun = Uj + 0.01f * Uj * (1.0f - Uj) * 0.1f;
        sx = fminf(fmaxf(sxn, 0.0f), 1.0f);
        su = fminf(fmaxf(sun, 0.0f), 1.0f);
        const float hp0 = su * sx * 0.1f;      // row parity == tid parity
        ((float4*)hpT)[tid * 2]     = make_float4(hp0, hp0, hp0, hp0);
        ((float4*)hpT)[tid * 2 + 1] = make_float4(hp0, hp0, hp0, hp0);
        const size_t ob = (size_t)(b0 + cb) * H_SZ + c0 + cc;      // t = 0
        out_sx[ob] = sx;
        out_su[ob] = su;
    }
    // x stagers: all 512 threads, (batch tid>>6, input col tid&63)
    float xreg = x[(size_t)(b0 + (tid >> 6)) * NIN_SZ + (tid & 63)];

    for (int t = 0; t < T_STEPS; ++t) {
        // stage x(t) into hpT input rows (prefetched previous step)
        hpT[(H_SZ + (tid & 63)) * BG + (tid >> 6)] = xreg;
        __syncthreads();                                   // bar0: hpT(t) ready

        const float nz = noise[((size_t)t * B_SZ + b0 + cb) * H_SZ + c0 + cc];

        // ---- phase B: matvec, W in registers, hpT broadcast reads ----
        float4 a0 = make_float4(0.f, 0.f, 0.f, 0.f);
        float4 a1 = a0, a2 = a0, a3 = a0, a4 = a0, a5 = a0, a6 = a0, a7 = a0;
        {
            const float4* hp4 = (const float4*)hpT;
            const int kb = kg * KR;
#pragma unroll
            for (int i = 0; i < KR; ++i) {
                const float4 hL = hp4[(kb + i) * 2];       // batches 0..3
                const float4 hH = hp4[(kb + i) * 2 + 1];   // batches 4..7
                const float4 wq = Wv[i];
                FMA4V(a0, wq, hL.x)
                FMA4V(a1, wq, hL.y)
                FMA4V(a2, wq, hL.z)
                FMA4V(a3, wq, hL.w)
                FMA4V(a4, wq, hH.x)
                FMA4V(a5, wq, hH.y)
                FMA4V(a6, wq, hH.z)
                FMA4V(a7, wq, hH.w)
            }
        }
        // prefetch x(t+1) while FMAs retire
        if (t + 1 < T_STEPS)
            xreg = x[((size_t)(t + 1) * B_SZ + b0 + (tid >> 6)) * NIN_SZ + (tid & 63)];

        // ---- cross-kg reduction: 4 kgs per wave via shuffles ----
        RED4(a0) RED4(a1) RED4(a2) RED4(a3)
        RED4(a4) RED4(a5) RED4(a6) RED4(a7)
        if ((tid & 48) == 0) {                 // lanes 0..15 of each wave
            *(float4*)&pbuf[(wv * BG + 0) * 64 + cg4] = a0;
            *(float4*)&pbuf[(wv * BG + 1) * 64 + cg4] = a1;
            *(float4*)&pbuf[(wv * BG + 2) * 64 + cg4] = a2;
            *(float4*)&pbuf[(wv * BG + 3) * 64 + cg4] = a3;
            *(float4*)&pbuf[(wv * BG + 4) * 64 + cg4] = a4;
            *(float4*)&pbuf[(wv * BG + 5) * 64 + cg4] = a5;
            *(float4*)&pbuf[(wv * BG + 6) * 64 + cg4] = a6;
            *(float4*)&pbuf[(wv * BG + 7) * 64 + cg4] = a7;
        }
        __syncthreads();                                   // bar1: pbuf ready

        // ---- phase C: combine, membrane, STP(t+1), publish tagged packet ----
        {
            float s = brnn_l[cc];
#pragma unroll
            for (int q = 0; q < 8; ++q)
                s += pbuf[(q * BG + cb) * 64 + cc];
            const float hn = fmaxf(0.9f * h + 0.1f * s + nz, 0.0f);
            h = hn;
            if (t + 1 < T_STEPS) {
                float sxn = sx + a_std * (1.0f - sx) - 0.01f * su * sx * hn;
                float sun = su + a_stf * (Uj - su)   + 0.01f * Uj * (1.0f - su) * hn;
                sx = fminf(fmaxf(sxn, 0.0f), 1.0f);
                su = fminf(fmaxf(sun, 0.0f), 1.0f);
                const float hp = su * sx * hn;
                const uint64_t pk =
                    ((uint64_t)(TAG_BASE + (unsigned)(t + 1)) << 32) |
                    (uint64_t)__float_as_uint(hp);
                uint64_t* sp = pkt +
                    ((size_t)((t + 1) & 1) * B_SZ + b0 + cb) * H_SZ + c0 + cc;
                asm volatile("global_store_dwordx2 %0, %1, off sc0 sc1"
                             :: "v"(sp), "v"(pk) : "memory");
            }
        }
        if (t + 1 >= T_STEPS) {
            out_h[((size_t)t * B_SZ + b0 + cb) * H_SZ + c0 + cc] = h;
            break;
        }

        // ---- outputs + drain: one vmcnt(0) covers outputs, prefetch and
        // the publish store, so poll iterations wait only on themselves ----
        {
            out_h[((size_t)t * B_SZ + b0 + cb) * H_SZ + c0 + cc] = h;
            const size_t ob = ((size_t)(t + 1) * B_SZ + b0 + cb) * H_SZ + c0 + cc;
            out_sx[ob] = sx;
            out_su[ob] = su;
        }
        asm volatile("s_waitcnt vmcnt(0)" ::: "memory");

        // ---- gather hp(t+1): poll 8 tagged slots (row tid x 8 batches) ----
        {
            const unsigned want = TAG_BASE + (unsigned)(t + 1);
            uint64_t* pr = pkt + ((size_t)((t + 1) & 1) * B_SZ + b0) * H_SZ + tid;
            uint64_t* q0 = pr;
            uint64_t* q1 = pr + 1 * H_SZ;
            uint64_t* q2 = pr + 2 * H_SZ;
            uint64_t* q3 = pr + 3 * H_SZ;
            uint64_t* q4 = pr + 4 * H_SZ;
            uint64_t* q5 = pr + 5 * H_SZ;
            uint64_t* q6 = pr + 6 * H_SZ;
            uint64_t* q7 = pr + 7 * H_SZ;
            uint64_t v0, v1, v2, v3, v4, v5, v6, v7;
            while (true) {
                asm volatile(
                    "global_load_dwordx2 %0, %8,  off sc0 sc1\n\t"
                    "global_load_dwordx2 %1, %9,  off sc0 sc1\n\t"
                    "global_load_dwordx2 %2, %10, off sc0 sc1\n\t"
                    "global_load_dwordx2 %3, %11, off sc0 sc1\n\t"
                    "global_load_dwordx2 %4, %12, off sc0 sc1\n\t"
                    "global_load_dwordx2 %5, %13, off sc0 sc1\n\t"
                    "global_load_dwordx2 %6, %14, off sc0 sc1\n\t"
                    "global_load_dwordx2 %7, %15, off sc0 sc1\n\t"
                    "s_waitcnt vmcnt(0)"
                    : "=&v"(v0), "=&v"(v1), "=&v"(v2), "=&v"(v3),
                      "=&v"(v4), "=&v"(v5), "=&v"(v6), "=&v"(v7)
                    : "v"(q0), "v"(q1), "v"(q2), "v"(q3),
                      "v"(q4), "v"(q5), "v"(q6), "v"(q7)
                    : "memory");
                const bool ok = ((unsigned)(v0 >> 32) == want) &
                                ((unsigned)(v1 >> 32) == want) &
                                ((unsigned)(v2 >> 32) == want) &
                                ((unsigned)(v3 >> 32) == want) &
                                ((unsigned)(v4 >> 32) == want) &
                                ((unsigned)(v5 >> 32) == want) &
                                ((unsigned)(v6 >> 32) == want) &
                                ((unsigned)(v7 >> 32) == want);
                if (__all(ok)) break;
            }
            ((float4*)hpT)[tid * 2] =
                make_float4(__uint_as_float((unsigned)v0),
                            __uint_as_float((unsigned)v1),
                            __uint_as_float((unsigned)v2),
                            __uint_as_float((unsigned)v3));
            ((float4*)hpT)[tid * 2 + 1] =
                make_float4(__uint_as_float((unsigned)v4),
                            __uint_as_float((unsigned)v5),
                            __uint_as_float((unsigned)v6),
                            __uint_as_float((unsigned)v7));
        }
        // next bar0 separates gather/x-stage writes from phase-B reads
    }
}

// ---------------------------------------------------------------------------
// logits[t,b,:] = h[t,b,:] @ relu(W_out) + bout  (overwrites the pkt scratch)
// ---------------------------------------------------------------------------
__global__ __launch_bounds__(256)
void logits_k(const float* __restrict__ h, const float* __restrict__ wout_raw,
              const float* __restrict__ bout, float* __restrict__ out) {
    __shared__ float wl[H_SZ * 17];    // padded stride 17
    __shared__ float bl[NOUT_SZ];
    const int tid = threadIdx.x;
    for (int i = tid; i < H_SZ * NOUT_SZ; i += 256)
        wl[(i >> 4) * 17 + (i & 15)] = fmaxf(wout_raw[i], 0.0f);
    if (tid < NOUT_SZ) bl[tid] = bout[tid];
    __syncthreads();
    const size_t row = (size_t)blockIdx.x * 16 + (tid >> 4);
    const int o = tid & 15;
    const float* hr = h + row * H_SZ;
    float s = bl[o];
#pragma unroll 8
    for (int jj = 0; jj < H_SZ; ++jj)
        s = fmaf(hr[jj], wl[jj * 17 + o], s);
    out[row * NOUT_SZ + o] = s;
}

extern "C" void kernel_launch(void* const* d_in, const int* in_sizes, int n_in,
                              void* d_out, int out_size, void* d_ws, size_t ws_size,
                              hipStream_t stream) {
    const float* x     = (const float*)d_in[0];
    const float* noise = (const float*)d_in[1];
    const float* W_in  = (const float*)d_in[2];
    const float* W_rnn = (const float*)d_in[3];
    const float* b_rnn = (const float*)d_in[4];
    const float* W_out = (const float*)d_in[5];
    const float* b_out = (const float*)d_in[6];

    float* out_logits = (float*)d_out;
    float* out_h  = out_logits + (size_t)T_STEPS * B_SZ * NOUT_SZ;
    float* out_sx = out_h  + (size_t)T_STEPS * B_SZ * H_SZ;
    float* out_su = out_sx + (size_t)T_STEPS * B_SZ * H_SZ;

    // pkt scratch: first 2 MB of the 6.55 MB logits region; fully
    // overwritten by logits_k afterwards.
    uint64_t* pkt = (uint64_t*)out_logits;

    biornn_main<<<NBLK, NTHR, 0, stream>>>(x, noise, W_rnn, W_in, b_rnn,
                                           pkt, out_h, out_sx, out_su);
    logits_k<<<(T_STEPS * B_SZ) / 16, 256, 0, stream>>>(
        out_h, W_out, b_out, out_logits);
}